// Round 6
// baseline (793.886 us; speedup 1.0000x reference)
//
#include <hip/hip_runtime.h>

// RNN-T joint: log_softmax(fc2(tanh(fc1(cat(enc,dec))))), fused.
// B=4, M=256, N=128, D=512, C=1024, JOINT=1024.
// ws: heb f32 [1024][512] (he+b1) | hdb bf16 [512][512] | w2p bf16 frag-packed
//
// R6: phases were ADDING (39us/gen = sum of floors) because each block did one
// generation then died. Now: persistent 16-wave blocks, 8 generations each,
// double-buffered hid LDS, one barrier/gen. K(i) overlaps stores(i-1) drain;
// stage(i+1) overlaps K(i) tail. B read once per 64-row gen (R4 lesson).

typedef __attribute__((ext_vector_type(8))) __bf16 bf16x8;
typedef __attribute__((ext_vector_type(8))) unsigned short u16x8;
typedef __attribute__((ext_vector_type(4))) float f32x4;

__device__ __forceinline__ float tanh_fast(float x) {
    float e = __expf(2.0f * x);
    return 1.0f - 2.0f / (e + 1.0f);
}
__device__ __forceinline__ float bf2f(unsigned short u) {
    return __builtin_bit_cast(float, (unsigned)u << 16);
}
__device__ __forceinline__ unsigned short f2bf(float f) {
    return __builtin_bit_cast(unsigned short, (__bf16)f);
}

// k_prep-only LDS swizzle
__device__ __forceinline__ int swz(int row, int kbyte) {
    return row * 1024 + (kbyte ^ ((row & 7) << 4));
}

__device__ __forceinline__ bf16x8 cvt8(float4 a, float4 b) {
    bf16x8 r;
    r[0] = (__bf16)a.x; r[1] = (__bf16)a.y; r[2] = (__bf16)a.z; r[3] = (__bf16)a.w;
    r[4] = (__bf16)b.x; r[5] = (__bf16)b.y; r[6] = (__bf16)b.z; r[7] = (__bf16)b.w;
    return r;
}

// ---------------------------------------------------------------------------
// Prep (validated R3/R5): blocks 0..15 -> heb = enc@w1enc^T + b1 (f32),
// 16..23 -> hdb = bf16(dec@w1dec^T), 24..39 -> w2 -> w2p (frag order:
// chunk = (ctile*16 + kt)*64 + lg*16 + lr, 8 bf16 each).
// ---------------------------------------------------------------------------
__global__ __launch_bounds__(512) void k_prep(
    const float* __restrict__ enc, const float* __restrict__ dec,
    const float* __restrict__ w1, const float* __restrict__ b1,
    const float* __restrict__ w2,
    float* __restrict__ heb, unsigned short* __restrict__ hdb,
    unsigned short* __restrict__ w2p)
{
    const int bid = blockIdx.x, tid = threadIdx.x;

    if (bid >= 24) {  // pack w2 -> w2p
        int t = (bid - 24) * 512 + tid;
        #pragma unroll
        for (int i = 0; i < 8; ++i) {
            int p = t + i * 8192;
            int c = p >> 6, kc = p & 63;
            const float4* s = (const float4*)(w2 + c * 512 + kc * 8);
            float4 a = s[0], bq = s[1];
            u16x8 o;
            o[0] = f2bf(a.x);  o[1] = f2bf(a.y);  o[2] = f2bf(a.z);  o[3] = f2bf(a.w);
            o[4] = f2bf(bq.x); o[5] = f2bf(bq.y); o[6] = f2bf(bq.z); o[7] = f2bf(bq.w);
            int kt = kc >> 2, lg = kc & 3;
            int chunk = ((c >> 4) * 16 + kt) * 64 + lg * 16 + (c & 15);
            *(u16x8*)(w2p + chunk * 8) = o;
        }
        return;
    }

    __shared__ uint4 ldsq[4096];
    char* lds = (char*)ldsq;

    const int r0 = (bid < 16 ? bid : bid - 16) * 64;
    const float* src = (bid < 16 ? enc : dec) + r0 * 512;
    const float* wsrc = w1 + (bid < 16 ? 0 : 512);

    const int lane = tid & 63, wid = tid >> 6;
    #pragma unroll
    for (int j = 0; j < 8; j++) {
        int row = wid * 8 + j;
        const float4* p = (const float4*)(src + row * 512 + lane * 8);
        *(bf16x8*)(lds + swz(row, lane * 16)) = cvt8(p[0], p[1]);
    }
    __syncthreads();

    const int lr = lane & 15, lg = lane >> 4;
    f32x4 acc[4][4];
    #pragma unroll
    for (int rt = 0; rt < 4; rt++)
        #pragma unroll
        for (int ct = 0; ct < 4; ct++)
            acc[rt][ct] = f32x4{0.f, 0.f, 0.f, 0.f};

    #pragma unroll 1
    for (int ks = 0; ks < 512; ks += 32) {
        bf16x8 af[4];
        #pragma unroll
        for (int rt = 0; rt < 4; rt++)
            af[rt] = *(const bf16x8*)(lds + swz(rt * 16 + lr, ks * 2 + lg * 16));
        #pragma unroll
        for (int ct = 0; ct < 4; ct++) {
            int col = wid * 64 + ct * 16 + lr;
            const float4* wp = (const float4*)(wsrc + col * 1024 + ks + lg * 8);
            bf16x8 bfr = cvt8(wp[0], wp[1]);
            #pragma unroll
            for (int rt = 0; rt < 4; rt++)
                acc[rt][ct] = __builtin_amdgcn_mfma_f32_16x16x32_bf16(af[rt], bfr, acc[rt][ct], 0, 0, 0);
        }
    }

    if (bid < 16) {
        float b1v[4];
        #pragma unroll
        for (int ct = 0; ct < 4; ct++) b1v[ct] = b1[wid * 64 + ct * 16 + lr];
        #pragma unroll
        for (int rt = 0; rt < 4; rt++)
            #pragma unroll
            for (int ct = 0; ct < 4; ct++)
                #pragma unroll
                for (int reg = 0; reg < 4; reg++)
                    heb[(r0 + rt * 16 + lg * 4 + reg) * 512 + wid * 64 + ct * 16 + lr] =
                        acc[rt][ct][reg] + b1v[ct];
    } else {
        #pragma unroll
        for (int rt = 0; rt < 4; rt++)
            #pragma unroll
            for (int ct = 0; ct < 4; ct++)
                #pragma unroll
                for (int reg = 0; reg < 4; reg++)
                    hdb[(r0 + rt * 16 + lg * 4 + reg) * 512 + wid * 64 + ct * 16 + lr] =
                        f2bf(acc[rt][ct][reg]);
    }
}

// ---------------------------------------------------------------------------
// Stage item g (64 rows x 512 k) as tanh(heb+hd) bf16 into ldbuf, frag-linear:
// region (RT*16+kt)*64 chunks; lane chunk = (row lr, kslice lg). Wave w covers
// row-tile RT=w>>2, kts (w&3)*4..+3. Conflict-free 1KB/wave ds_writes.
// ---------------------------------------------------------------------------
__device__ __forceinline__ void stage_tile(
    int g, char* ldbuf, const float* heb, const unsigned short* hdb,
    int w, int lane, int lr, int lg)
{
    const int RT = w >> 2, kt0 = (w & 3) * 4;
    const unsigned short* hb =
        hdb + (size_t)((g >> 9) * 128 + (g & 1) * 64 + RT * 16 + lr) * 512 + lg * 8;
    const float* ep = heb + (size_t)(g >> 1) * 512 + lg * 8;
    char* ld = ldbuf + (RT * 16 * 64 + lane) * 16;
    #pragma unroll
    for (int it = 0; it < 4; ++it) {
        int kt = kt0 + it;
        u16x8 hv = *(const u16x8*)(hb + kt * 32);
        float4 e0 = *(const float4*)(ep + kt * 32);
        float4 e1 = *(const float4*)(ep + kt * 32 + 4);
        bf16x8 xo;
        xo[0] = (__bf16)tanh_fast(bf2f(hv[0]) + e0.x);
        xo[1] = (__bf16)tanh_fast(bf2f(hv[1]) + e0.y);
        xo[2] = (__bf16)tanh_fast(bf2f(hv[2]) + e0.z);
        xo[3] = (__bf16)tanh_fast(bf2f(hv[3]) + e0.w);
        xo[4] = (__bf16)tanh_fast(bf2f(hv[4]) + e1.x);
        xo[5] = (__bf16)tanh_fast(bf2f(hv[5]) + e1.y);
        xo[6] = (__bf16)tanh_fast(bf2f(hv[6]) + e1.z);
        xo[7] = (__bf16)tanh_fast(bf2f(hv[7]) + e1.w);
        *(bf16x8*)(ld + kt * 1024) = xo;
    }
}

// ---------------------------------------------------------------------------
// Main: persistent block = 16 waves, 8 items of 64 rows x 1024 classes.
// Swapped MFMA (w2 = A, hid = B): lane holds (row n = rt*16+lr,
// classes (w*4+ct)*16 + lg*4 + 0..3) -> in-lane softmax, float4 stores.
// One barrier per generation; hid LDS double-buffered; red buffers by parity.
// ---------------------------------------------------------------------------
__global__ __launch_bounds__(1024, 4) void k_main(
    const float* __restrict__ heb, const unsigned short* __restrict__ hdb,
    const float* __restrict__ b2, const unsigned short* __restrict__ w2p,
    float* __restrict__ out)
{
    __shared__ uint4 ldsq[2][4096];        // 2 x 64 KB hid buffers
    __shared__ float redm[2][64][16];      // per-parity row-max partials
    __shared__ float reds[2][64][16];      // per-parity row-sumexp partials

    const int bid = blockIdx.x, tid = threadIdx.x;
    const int lane = tid & 63, w = tid >> 6, lr = lane & 15, lg = lane >> 4;

    const char* pw = (const char*)w2p + (w << 16) + (lane << 4);

    stage_tile(bid * 8, (char*)&ldsq[0][0], heb, hdb, w, lane, lr, lg);
    __syncthreads();

    #pragma unroll 1
    for (int j = 0; j < 8; ++j) {
        const int g = bid * 8 + j, s = j & 1;
        const char* la = (const char*)&ldsq[s][0] + (lane << 4);

        // ---- K-loop: B (w2) reg-double-buffered from L2, hid from LDS ----
        f32x4 acc[4][4];
        #pragma unroll
        for (int rt = 0; rt < 4; rt++)
            #pragma unroll
            for (int ct = 0; ct < 4; ct++)
                acc[rt][ct] = f32x4{0.f, 0.f, 0.f, 0.f};

        bf16x8 aw[2][4];
        #pragma unroll
        for (int ct = 0; ct < 4; ct++)
            aw[0][ct] = *(const bf16x8*)(pw + ct * 16384);

        #pragma unroll
        for (int kt = 0; kt < 16; ++kt) {
            if (kt < 15) {
                #pragma unroll
                for (int ct = 0; ct < 4; ct++)
                    aw[(kt + 1) & 1][ct] = *(const bf16x8*)(pw + ct * 16384 + (kt + 1) * 1024);
            }
            bf16x8 h[4];
            #pragma unroll
            for (int rt = 0; rt < 4; rt++)
                h[rt] = *(const bf16x8*)(la + (rt * 16 + kt) * 1024);
            __builtin_amdgcn_s_setprio(1);
            #pragma unroll
            for (int ct = 0; ct < 4; ct++)
                #pragma unroll
                for (int rt = 0; rt < 4; rt++)
                    acc[rt][ct] = __builtin_amdgcn_mfma_f32_16x16x32_bf16(
                        aw[kt & 1][ct], h[rt], acc[rt][ct], 0, 0, 0);
            __builtin_amdgcn_s_setprio(0);
        }

        // ---- stage next item into the other LDS buffer ----
        if (j < 7)
            stage_tile(g + 1, (char*)&ldsq[s ^ 1][0], heb, hdb, w, lane, lr, lg);

        // ---- +b2 ----
        #pragma unroll
        for (int ct = 0; ct < 4; ct++) {
            float4 bq = *(const float4*)(b2 + (w * 4 + ct) * 16 + lg * 4);
            #pragma unroll
            for (int rt = 0; rt < 4; rt++) {
                acc[rt][ct][0] += bq.x; acc[rt][ct][1] += bq.y;
                acc[rt][ct][2] += bq.z; acc[rt][ct][3] += bq.w;
            }
        }

        // ---- per-wave online (max, sumexp) per row; merge across lg ----
        #pragma unroll
        for (int rt = 0; rt < 4; rt++) {
            float pm[4];
            #pragma unroll
            for (int ct = 0; ct < 4; ct++)
                pm[ct] = fmaxf(fmaxf(acc[rt][ct][0], acc[rt][ct][1]),
                               fmaxf(acc[rt][ct][2], acc[rt][ct][3]));
            float m = fmaxf(fmaxf(pm[0], pm[1]), fmaxf(pm[2], pm[3]));
            float sv = 0.f;
            #pragma unroll
            for (int ct = 0; ct < 4; ct++) {
                sv += __expf(acc[rt][ct][0] - m);
                sv += __expf(acc[rt][ct][1] - m);
                sv += __expf(acc[rt][ct][2] - m);
                sv += __expf(acc[rt][ct][3] - m);
            }
            float mo = __shfl_xor(m, 16), so = __shfl_xor(sv, 16);
            float mn = fmaxf(m, mo);
            sv = sv * __expf(m - mn) + so * __expf(mo - mn);
            m = mn;
            mo = __shfl_xor(m, 32); so = __shfl_xor(sv, 32);
            mn = fmaxf(m, mo);
            sv = sv * __expf(m - mn) + so * __expf(mo - mn);
            m = mn;
            if (lg == 0) {
                redm[s][rt * 16 + lr][w] = m;
                reds[s][rt * 16 + lr][w] = sv;
            }
        }
        __syncthreads();

        // ---- combine 16 wave-partials -> logZ; store float4s ----
        const size_t rowbase = (size_t)g * 64;
        #pragma unroll
        for (int rt = 0; rt < 4; rt++) {
            int r = rt * 16 + lr;
            const float4* mp = (const float4*)&redm[s][r][0];
            const float4* sp = (const float4*)&reds[s][r][0];
            float4 m0 = mp[0], m1 = mp[1], m2 = mp[2], m3 = mp[3];
            float4 s0 = sp[0], s1 = sp[1], s2 = sp[2], s3 = sp[3];
            float M = fmaxf(fmaxf(fmaxf(m0.x, m0.y), fmaxf(m0.z, m0.w)),
                            fmaxf(fmaxf(m1.x, m1.y), fmaxf(m1.z, m1.w)));
            M = fmaxf(M, fmaxf(fmaxf(fmaxf(m2.x, m2.y), fmaxf(m2.z, m2.w)),
                               fmaxf(fmaxf(m3.x, m3.y), fmaxf(m3.z, m3.w))));
            float S = s0.x * __expf(m0.x - M) + s0.y * __expf(m0.y - M)
                    + s0.z * __expf(m0.z - M) + s0.w * __expf(m0.w - M)
                    + s1.x * __expf(m1.x - M) + s1.y * __expf(m1.y - M)
                    + s1.z * __expf(m1.z - M) + s1.w * __expf(m1.w - M)
                    + s2.x * __expf(m2.x - M) + s2.y * __expf(m2.y - M)
                    + s2.z * __expf(m2.z - M) + s2.w * __expf(m2.w - M)
                    + s3.x * __expf(m3.x - M) + s3.y * __expf(m3.y - M)
                    + s3.z * __expf(m3.z - M) + s3.w * __expf(m3.w - M);
            float logZ = M + __logf(S);

            float* orow = out + (rowbase + r) * 1024 + lg * 4;
            #pragma unroll
            for (int ct = 0; ct < 4; ct++) {
                f32x4 v = acc[rt][ct];
                float4 o;
                o.x = v[0] - logZ; o.y = v[1] - logZ;
                o.z = v[2] - logZ; o.w = v[3] - logZ;
                *(float4*)(orow + (w * 4 + ct) * 16) = o;
            }
        }
    }
}

extern "C" void kernel_launch(void* const* d_in, const int* in_sizes, int n_in,
                              void* d_out, int out_size, void* d_ws, size_t ws_size,
                              hipStream_t stream) {
    const float* enc = (const float*)d_in[0];
    const float* dec = (const float*)d_in[1];
    const float* w1  = (const float*)d_in[2];
    const float* b1  = (const float*)d_in[3];
    const float* w2  = (const float*)d_in[4];
    const float* b2  = (const float*)d_in[5];

    float* heb = (float*)d_ws;                                   // 2 MB
    unsigned short* hdb = (unsigned short*)(heb + 1024 * 512);   // 0.5 MB
    unsigned short* w2p = hdb + 512 * 512;                       // 1 MB

    k_prep<<<40, 512, 0, stream>>>(enc, dec, w1, b1, w2, heb, hdb, w2p);
    k_main<<<256, 1024, 0, stream>>>(heb, hdb, b2, w2p, (float*)d_out);
}

// Round 7
// 291.170 us; speedup vs baseline: 2.7265x; 2.7265x over previous
//
#include <hip/hip_runtime.h>

// RNN-T joint: log_softmax(fc2(tanh(fc1(cat(enc,dec))))), fused.
// B=4, M=256, N=128, D=512, C=1024, JOINT=1024.
// ws: heb f32 [1024][512] (he+b1) | hdb bf16 [512][512] | w2p bf16 frag-packed
//
// R7 = R5 structure (32-row x 1024-col blocks, 8 waves, swapped MFMA,
// 2 blocks/CU) + two changes:
//  1. NONTEMPORAL output stores: output never allocates in XCD L2, so
//     w2p+heb+hdb (3.5 MB) stay L2-resident; B-loads are L2 hits even when
//     blocks desync (R6 lesson: store stream was flushing w2p every gen).
//  2. Bijective XCD swizzle: the 4 blocks sharing one heb row -> same XCD.

typedef __attribute__((ext_vector_type(8))) __bf16 bf16x8;
typedef __attribute__((ext_vector_type(8))) unsigned short u16x8;
typedef __attribute__((ext_vector_type(4))) float f32x4;

__device__ __forceinline__ float tanh_fast(float x) {
    float e = __expf(2.0f * x);
    return 1.0f - 2.0f / (e + 1.0f);
}
__device__ __forceinline__ float bf2f(unsigned short u) {
    return __builtin_bit_cast(float, (unsigned)u << 16);
}
__device__ __forceinline__ unsigned short f2bf(float f) {
    return __builtin_bit_cast(unsigned short, (__bf16)f);
}

// k_prep-only LDS swizzle
__device__ __forceinline__ int swz(int row, int kbyte) {
    return row * 1024 + (kbyte ^ ((row & 7) << 4));
}

__device__ __forceinline__ bf16x8 cvt8(float4 a, float4 b) {
    bf16x8 r;
    r[0] = (__bf16)a.x; r[1] = (__bf16)a.y; r[2] = (__bf16)a.z; r[3] = (__bf16)a.w;
    r[4] = (__bf16)b.x; r[5] = (__bf16)b.y; r[6] = (__bf16)b.z; r[7] = (__bf16)b.w;
    return r;
}

// ---------------------------------------------------------------------------
// Prep (validated R3/R5): blocks 0..15 -> heb = enc@w1enc^T + b1 (f32),
// 16..23 -> hdb = bf16(dec@w1dec^T), 24..39 -> w2 -> w2p (frag order:
// chunk = (ctile*16 + kt)*64 + lg*16 + lr, 8 bf16 each).
// ---------------------------------------------------------------------------
__global__ __launch_bounds__(512) void k_prep(
    const float* __restrict__ enc, const float* __restrict__ dec,
    const float* __restrict__ w1, const float* __restrict__ b1,
    const float* __restrict__ w2,
    float* __restrict__ heb, unsigned short* __restrict__ hdb,
    unsigned short* __restrict__ w2p)
{
    const int bid = blockIdx.x, tid = threadIdx.x;

    if (bid >= 24) {  // pack w2 -> w2p
        int t = (bid - 24) * 512 + tid;
        #pragma unroll
        for (int i = 0; i < 8; ++i) {
            int p = t + i * 8192;
            int c = p >> 6, kc = p & 63;
            const float4* s = (const float4*)(w2 + c * 512 + kc * 8);
            float4 a = s[0], bq = s[1];
            u16x8 o;
            o[0] = f2bf(a.x);  o[1] = f2bf(a.y);  o[2] = f2bf(a.z);  o[3] = f2bf(a.w);
            o[4] = f2bf(bq.x); o[5] = f2bf(bq.y); o[6] = f2bf(bq.z); o[7] = f2bf(bq.w);
            int kt = kc >> 2, lg = kc & 3;
            int chunk = ((c >> 4) * 16 + kt) * 64 + lg * 16 + (c & 15);
            *(u16x8*)(w2p + chunk * 8) = o;
        }
        return;
    }

    __shared__ uint4 ldsq[4096];
    char* lds = (char*)ldsq;

    const int r0 = (bid < 16 ? bid : bid - 16) * 64;
    const float* src = (bid < 16 ? enc : dec) + r0 * 512;
    const float* wsrc = w1 + (bid < 16 ? 0 : 512);

    const int lane = tid & 63, wid = tid >> 6;
    #pragma unroll
    for (int j = 0; j < 8; j++) {
        int row = wid * 8 + j;
        const float4* p = (const float4*)(src + row * 512 + lane * 8);
        *(bf16x8*)(lds + swz(row, lane * 16)) = cvt8(p[0], p[1]);
    }
    __syncthreads();

    const int lr = lane & 15, lg = lane >> 4;
    f32x4 acc[4][4];
    #pragma unroll
    for (int rt = 0; rt < 4; rt++)
        #pragma unroll
        for (int ct = 0; ct < 4; ct++)
            acc[rt][ct] = f32x4{0.f, 0.f, 0.f, 0.f};

    #pragma unroll 1
    for (int ks = 0; ks < 512; ks += 32) {
        bf16x8 af[4];
        #pragma unroll
        for (int rt = 0; rt < 4; rt++)
            af[rt] = *(const bf16x8*)(lds + swz(rt * 16 + lr, ks * 2 + lg * 16));
        #pragma unroll
        for (int ct = 0; ct < 4; ct++) {
            int col = wid * 64 + ct * 16 + lr;
            const float4* wp = (const float4*)(wsrc + col * 1024 + ks + lg * 8);
            bf16x8 bfr = cvt8(wp[0], wp[1]);
            #pragma unroll
            for (int rt = 0; rt < 4; rt++)
                acc[rt][ct] = __builtin_amdgcn_mfma_f32_16x16x32_bf16(af[rt], bfr, acc[rt][ct], 0, 0, 0);
        }
    }

    if (bid < 16) {
        float b1v[4];
        #pragma unroll
        for (int ct = 0; ct < 4; ct++) b1v[ct] = b1[wid * 64 + ct * 16 + lr];
        #pragma unroll
        for (int rt = 0; rt < 4; rt++)
            #pragma unroll
            for (int ct = 0; ct < 4; ct++)
                #pragma unroll
                for (int reg = 0; reg < 4; reg++)
                    heb[(r0 + rt * 16 + lg * 4 + reg) * 512 + wid * 64 + ct * 16 + lr] =
                        acc[rt][ct][reg] + b1v[ct];
    } else {
        #pragma unroll
        for (int rt = 0; rt < 4; rt++)
            #pragma unroll
            for (int ct = 0; ct < 4; ct++)
                #pragma unroll
                for (int reg = 0; reg < 4; reg++)
                    hdb[(r0 + rt * 16 + lg * 4 + reg) * 512 + wid * 64 + ct * 16 + lr] =
                        f2bf(acc[rt][ct][reg]);
    }
}

// ---------------------------------------------------------------------------
// K sweep for column group G (ctiles w*8+G*4 .. +3), all 16 kt, both row tiles.
// aw = w2 fragments (A operand, reg double-buffered from L2); hid from LDS (B).
// ---------------------------------------------------------------------------
template<int G>
__device__ __forceinline__ void kgroup(const char* pwb, const char* la,
                                       f32x4 (&acc)[2][8]) {
    const char* pw = pwb + G * 65536;
    bf16x8 aw[2][4];
    #pragma unroll
    for (int ct = 0; ct < 4; ct++)
        aw[0][ct] = *(const bf16x8*)(pw + ct * 16384);
    #pragma unroll
    for (int kt = 0; kt < 16; ++kt) {
        if (kt < 15) {
            #pragma unroll
            for (int ct = 0; ct < 4; ct++)
                aw[(kt + 1) & 1][ct] = *(const bf16x8*)(pw + ct * 16384 + (kt + 1) * 1024);
        }
        bf16x8 h0 = *(const bf16x8*)(la + kt * 1024);
        bf16x8 h1 = *(const bf16x8*)(la + 16384 + kt * 1024);
        __builtin_amdgcn_s_setprio(1);
        #pragma unroll
        for (int ct = 0; ct < 4; ct++) {
            acc[0][G * 4 + ct] = __builtin_amdgcn_mfma_f32_16x16x32_bf16(
                aw[kt & 1][ct], h0, acc[0][G * 4 + ct], 0, 0, 0);
            acc[1][G * 4 + ct] = __builtin_amdgcn_mfma_f32_16x16x32_bf16(
                aw[kt & 1][ct], h1, acc[1][G * 4 + ct], 0, 0, 0);
        }
        __builtin_amdgcn_s_setprio(0);
    }
}

// ---------------------------------------------------------------------------
// Main: block = 32 rows (one (b,m), 32 n's) x 1024 classes, 8 waves.
// Swapped MFMA: lane holds (row n = rt*16+lr, classes ctile*16 + lg*4 + 0..3).
// Output stores are NONTEMPORAL (bypass/evict-first in L2).
// ---------------------------------------------------------------------------
__global__ __launch_bounds__(512, 4) void k_main(
    const float* __restrict__ heb, const unsigned short* __restrict__ hdb,
    const float* __restrict__ b2, const unsigned short* __restrict__ w2p,
    float* __restrict__ out)
{
    __shared__ uint4 ldsq[2048];          // 32 KB hid tile (2 rt x 16 kt x 1KB)
    __shared__ float redm[32][8];         // per-wave row max
    __shared__ float reds[32][8];         // per-wave row sum(exp)
    char* lds = (char*)ldsq;

    // XCD-bijective remap (4096 % 8 == 0): 512 consecutive work items per XCD;
    // the 4 blocks sharing one heb row land on the same XCD L2.
    const int bid = ((blockIdx.x & 7) << 9) | (blockIdx.x >> 3);
    const int tid = threadIdx.x;
    const int bm = bid >> 2, nq = bid & 3;
    const int b = bm >> 8;
    const int lane = tid & 63, w = tid >> 6, lr = lane & 15, lg = lane >> 4;

    // ---- stage hid = tanh(heb + hd) bf16, fragment-linear ----
    {
        const int rt = w >> 2, kt0 = (w & 3) * 4;
        const unsigned short* hb =
            hdb + (size_t)(b * 128 + nq * 32 + rt * 16 + lr) * 512 + lg * 8;
        const float* ep = heb + (size_t)bm * 512 + lg * 8;
        char* ld = lds + (rt * 16 * 64 + lane) * 16;
        #pragma unroll
        for (int it = 0; it < 4; ++it) {
            int kt = kt0 + it;
            u16x8 hv = *(const u16x8*)(hb + kt * 32);
            float4 e0 = *(const float4*)(ep + kt * 32);
            float4 e1 = *(const float4*)(ep + kt * 32 + 4);
            bf16x8 xo;
            xo[0] = (__bf16)tanh_fast(bf2f(hv[0]) + e0.x);
            xo[1] = (__bf16)tanh_fast(bf2f(hv[1]) + e0.y);
            xo[2] = (__bf16)tanh_fast(bf2f(hv[2]) + e0.z);
            xo[3] = (__bf16)tanh_fast(bf2f(hv[3]) + e0.w);
            xo[4] = (__bf16)tanh_fast(bf2f(hv[4]) + e1.x);
            xo[5] = (__bf16)tanh_fast(bf2f(hv[5]) + e1.y);
            xo[6] = (__bf16)tanh_fast(bf2f(hv[6]) + e1.z);
            xo[7] = (__bf16)tanh_fast(bf2f(hv[7]) + e1.w);
            *(bf16x8*)(ld + kt * 1024) = xo;
        }
    }
    __syncthreads();

    const char* pwb = (const char*)w2p + ((size_t)w << 17) + (lane << 4);
    const char* la = lds + (lane << 4);

    f32x4 acc[2][8];
    #pragma unroll
    for (int rt = 0; rt < 2; rt++)
        #pragma unroll
        for (int j = 0; j < 8; j++)
            acc[rt][j] = f32x4{0.f, 0.f, 0.f, 0.f};

    kgroup<0>(pwb, la, acc);
    kgroup<1>(pwb, la, acc);

    // ---- +b2 (classes ctile*16 + lg*4 + 0..3) ----
    #pragma unroll
    for (int j = 0; j < 8; j++) {
        float4 bq = *(const float4*)(b2 + (w * 8 + j) * 16 + lg * 4);
        acc[0][j][0] += bq.x; acc[0][j][1] += bq.y; acc[0][j][2] += bq.z; acc[0][j][3] += bq.w;
        acc[1][j][0] += bq.x; acc[1][j][1] += bq.y; acc[1][j][2] += bq.z; acc[1][j][3] += bq.w;
    }

    // ---- per-wave row stats: 32 values in-lane, then merge across lg ----
    float mw[2], sw[2];
    #pragma unroll
    for (int rt = 0; rt < 2; rt++) {
        float pm[8];
        #pragma unroll
        for (int j = 0; j < 8; j++)
            pm[j] = fmaxf(fmaxf(acc[rt][j][0], acc[rt][j][1]),
                          fmaxf(acc[rt][j][2], acc[rt][j][3]));
        float m = fmaxf(fmaxf(fmaxf(pm[0], pm[1]), fmaxf(pm[2], pm[3])),
                        fmaxf(fmaxf(pm[4], pm[5]), fmaxf(pm[6], pm[7])));
        float s = 0.f;
        #pragma unroll
        for (int j = 0; j < 8; j++) {
            s += __expf(acc[rt][j][0] - m);
            s += __expf(acc[rt][j][1] - m);
            s += __expf(acc[rt][j][2] - m);
            s += __expf(acc[rt][j][3] - m);
        }
        float mo = __shfl_xor(m, 16), so = __shfl_xor(s, 16);
        float mn = fmaxf(m, mo);
        s = s * __expf(m - mn) + so * __expf(mo - mn);
        m = mn;
        mo = __shfl_xor(m, 32); so = __shfl_xor(s, 32);
        mn = fmaxf(m, mo);
        s = s * __expf(m - mn) + so * __expf(mo - mn);
        m = mn;
        mw[rt] = m; sw[rt] = s;
    }
    if (lane < 16) {
        redm[lr][w]      = mw[0]; reds[lr][w]      = sw[0];
        redm[16 + lr][w] = mw[1]; reds[16 + lr][w] = sw[1];
    }
    __syncthreads();

    // ---- combine 8 wave-partials -> logZ per row ----
    float logZ[2];
    #pragma unroll
    for (int rt = 0; rt < 2; rt++) {
        int r = rt * 16 + lr;
        float4 ma = *(const float4*)&redm[r][0];
        float4 mb = *(const float4*)&redm[r][4];
        float4 sa = *(const float4*)&reds[r][0];
        float4 sb = *(const float4*)&reds[r][4];
        float M = fmaxf(fmaxf(fmaxf(ma.x, ma.y), fmaxf(ma.z, ma.w)),
                        fmaxf(fmaxf(mb.x, mb.y), fmaxf(mb.z, mb.w)));
        float S = sa.x * __expf(ma.x - M) + sa.y * __expf(ma.y - M)
                + sa.z * __expf(ma.z - M) + sa.w * __expf(ma.w - M)
                + sb.x * __expf(mb.x - M) + sb.y * __expf(mb.y - M)
                + sb.z * __expf(mb.z - M) + sb.w * __expf(mb.w - M);
        logZ[rt] = M + __logf(S);
    }

    // ---- store: NONTEMPORAL float4 per (rt, ctile) ----
    const size_t rowbase = (size_t)bm * 128 + nq * 32;
    #pragma unroll
    for (int rt = 0; rt < 2; rt++) {
        float* orow = out + (rowbase + rt * 16 + lr) * 1024 + lg * 4;
        #pragma unroll
        for (int j = 0; j < 8; j++) {
            f32x4 v = acc[rt][j];
            f32x4 o;
            o[0] = v[0] - logZ[rt]; o[1] = v[1] - logZ[rt];
            o[2] = v[2] - logZ[rt]; o[3] = v[3] - logZ[rt];
            __builtin_nontemporal_store(o, (f32x4*)(orow + (w * 8 + j) * 16));
        }
    }
}

extern "C" void kernel_launch(void* const* d_in, const int* in_sizes, int n_in,
                              void* d_out, int out_size, void* d_ws, size_t ws_size,
                              hipStream_t stream) {
    const float* enc = (const float*)d_in[0];
    const float* dec = (const float*)d_in[1];
    const float* w1  = (const float*)d_in[2];
    const float* b1  = (const float*)d_in[3];
    const float* w2  = (const float*)d_in[4];
    const float* b2  = (const float*)d_in[5];

    float* heb = (float*)d_ws;                                   // 2 MB
    unsigned short* hdb = (unsigned short*)(heb + 1024 * 512);   // 0.5 MB
    unsigned short* w2p = hdb + 512 * 512;                       // 1 MB

    k_prep<<<40, 512, 0, stream>>>(enc, dec, w1, b1, w2, heb, hdb, w2p);
    k_main<<<4096, 512, 0, stream>>>(heb, hdb, b2, w2p, (float*)d_out);
}